// Round 3
// baseline (1065.020 us; speedup 1.0000x reference)
//
#include <hip/hip_runtime.h>

// Problem constants (match reference)
constexpr int U_ = 256;
constexpr int I_ = 512;
constexpr int J_ = 31;          // neighbors
constexpr int UI = U_ * I_;     // 131072 (u,i) pairs
// E_IN=3, N_EMB=10, N_FIT=32, K=2

// LDS weight layout (float offsets). Wf1/Wf2/Wf3 bases are 16B-aligned.
constexpr int L_W1  = 0;      // [3][10]
constexpr int L_B1  = 30;     // [10]
constexpr int L_W2  = 40;     // [10][10]
constexpr int L_B2  = 140;    // [10]
constexpr int L_WF1 = 152;    // [20][32]
constexpr int L_BF1 = 792;    // [32]
constexpr int L_WF2 = 824;    // [32][32]
constexpr int L_BF2 = 1848;   // [32]
constexpr int L_WF3 = 1880;   // [32]
constexpr int L_BF3 = 1912;   // [1]
constexpr int L_TOT = 1916;

struct Nb { float s0, s1, s2; float4 r; };

__device__ __forceinline__ Nb load_nb(const float* __restrict__ sg,
                                      const float* __restrict__ rr, int j) {
    Nb d;
    d.s0 = sg[j * 3 + 0];
    d.s1 = sg[j * 3 + 1];
    d.s2 = sg[j * 3 + 2];
    d.r  = *reinterpret_cast<const float4*>(rr + j * 4);
    return d;
}

__global__ __launch_bounds__(256, 4) void dqn_v3(
    const float* __restrict__ Sg,  const float* __restrict__ R,
    const float* __restrict__ W1,  const float* __restrict__ b1,
    const float* __restrict__ W2,  const float* __restrict__ b2,
    const float* __restrict__ Wf1, const float* __restrict__ bf1,
    const float* __restrict__ Wf2, const float* __restrict__ bf2,
    const float* __restrict__ Wf3, const float* __restrict__ bf3,
    float* __restrict__ out)
{
    __shared__ float wlds[L_TOT];
    const int tid = threadIdx.x;

    // One-time cooperative weight stage into LDS
    if (tid < 30)  wlds[L_W1 + tid] = W1[tid];
    if (tid < 10)  wlds[L_B1 + tid] = b1[tid];
    if (tid < 100) wlds[L_W2 + tid] = W2[tid];
    if (tid >= 128 && tid < 138) wlds[L_B2 + tid - 128] = b2[tid - 128];
    for (int i = tid; i < 640; i += 256)  wlds[L_WF1 + i] = Wf1[i];
    for (int i = tid; i < 1024; i += 256) wlds[L_WF2 + i] = Wf2[i];
    if (tid >= 160 && tid < 192) wlds[L_BF1 + tid - 160] = bf1[tid - 160];
    if (tid >= 192 && tid < 224) wlds[L_BF2 + tid - 192] = bf2[tid - 192];
    if (tid >= 224 && tid < 256) wlds[L_WF3 + tid - 224] = Wf3[tid - 224];
    if (tid == 127) wlds[L_BF3] = bf3[0];
    __syncthreads();

    const int gt   = blockIdx.x * 256 + tid;
    const int pair = gt >> 1;
    const int half = gt & 1;          // p-channel half: owns p in [5*half, 5*half+5)
    const int p0   = half * 5;

    const float* sg = Sg + (size_t)pair * (J_ * 3);
    const float* rr = R  + (size_t)pair * (J_ * 4);

    // Per-lane slice of embedding layer-1 weights (from LDS)
    float w1[3][5], c1[5];
    #pragma unroll
    for (int k = 0; k < 3; ++k)
        #pragma unroll
        for (int i = 0; i < 5; ++i) w1[k][i] = wlds[L_W1 + k * 10 + p0 + i];
    #pragma unroll
    for (int i = 0; i < 5; ++i) c1[i] = wlds[L_B1 + p0 + i];

    // M[l][i] = sum_j R_j[l] * h_j[p0+i]  (lane's 5 channels); Rs[l] = sum_j R_j[l]
    float M[4][5];
    float Rs[4] = {0.f, 0.f, 0.f, 0.f};
    #pragma unroll
    for (int l = 0; l < 4; ++l)
        #pragma unroll
        for (int i = 0; i < 5; ++i) M[l][i] = 0.f;

    auto process = [&](const Nb& nb) {
        float h[5];
        #pragma unroll
        for (int i = 0; i < 5; ++i) {
            float t = c1[i] + nb.s0 * w1[0][i] + nb.s1 * w1[1][i] + nb.s2 * w1[2][i];
            h[i] = t > 0.f ? t : 0.f;
        }
        Rs[0] += nb.r.x; Rs[1] += nb.r.y; Rs[2] += nb.r.z; Rs[3] += nb.r.w;
        #pragma unroll
        for (int i = 0; i < 5; ++i) {
            M[0][i] += nb.r.x * h[i];
            M[1][i] += nb.r.y * h[i];
            M[2][i] += nb.r.z * h[i];
            M[3][i] += nb.r.w * h[i];
        }
    };

    // Depth-2 software pipeline over 31 neighbors
    Nb A = load_nb(sg, rr, 0);
    Nb B = load_nb(sg, rr, 1);
    #pragma unroll 1
    for (int jj = 0; jj + 1 < J_; jj += 2) {
        Nb C  = load_nb(sg, rr, jj + 2);
        Nb D2 = C;
        if (jj + 3 < J_) D2 = load_nb(sg, rr, jj + 3);
        process(A);
        process(B);
        A = C;
        B = D2;
    }
    process(A);   // j = 30

    // Partial T2 over this lane's 5 p-rows; bias term counted on half 0 only.
    float T2[4][10];
    #pragma unroll
    for (int l = 0; l < 4; ++l)
        #pragma unroll
        for (int n = 0; n < 10; ++n)
            T2[l][n] = (half == 0) ? Rs[l] * wlds[L_B2 + n] : 0.f;
    #pragma unroll
    for (int i = 0; i < 5; ++i) {
        float w2row[10];
        #pragma unroll
        for (int n = 0; n < 10; ++n) w2row[n] = wlds[L_W2 + (p0 + i) * 10 + n];
        #pragma unroll
        for (int l = 0; l < 4; ++l) {
            float m = M[l][i];
            #pragma unroll
            for (int n = 0; n < 10; ++n) T2[l][n] += m * w2row[n];
        }
    }
    // Merge the two p-halves: both lanes end with the full T2.
    #pragma unroll
    for (int l = 0; l < 4; ++l)
        #pragma unroll
        for (int n = 0; n < 10; ++n) T2[l][n] += __shfl_xor(T2[l][n], 1);

    // D[k*10+n] = sum_l T2[l][k] * T2[l][n], k<2 (T1 == T2^T, never computed)
    float D[20];
    #pragma unroll
    for (int k = 0; k < 2; ++k)
        #pragma unroll
        for (int n = 0; n < 10; ++n)
            D[k * 10 + n] = T2[0][k] * T2[0][n] + T2[1][k] * T2[1][n]
                          + T2[2][k] * T2[2][n] + T2[3][k] * T2[3][n];

    // Fit MLP 20->32->32->1, weights broadcast from LDS (both lanes redundant)
    const float4* wf1 = reinterpret_cast<const float4*>(&wlds[L_WF1]);
    const float4* wf2 = reinterpret_cast<const float4*>(&wlds[L_WF2]);
    const float4* wf3 = reinterpret_cast<const float4*>(&wlds[L_WF3]);

    float f1[32];
    #pragma unroll
    for (int o = 0; o < 32; ++o) f1[o] = wlds[L_BF1 + o];
    #pragma unroll
    for (int kk = 0; kk < 20; ++kk) {
        float d = D[kk];
        #pragma unroll
        for (int v = 0; v < 8; ++v) {
            float4 w = wf1[kk * 8 + v];
            f1[4 * v + 0] += d * w.x;
            f1[4 * v + 1] += d * w.y;
            f1[4 * v + 2] += d * w.z;
            f1[4 * v + 3] += d * w.w;
        }
    }
    #pragma unroll
    for (int o = 0; o < 32; ++o) f1[o] = f1[o] > 0.f ? f1[o] : 0.f;

    float f2[32];
    #pragma unroll
    for (int o = 0; o < 32; ++o) f2[o] = wlds[L_BF2 + o];
    #pragma unroll
    for (int kk = 0; kk < 32; ++kk) {
        float d = f1[kk];
        #pragma unroll
        for (int v = 0; v < 8; ++v) {
            float4 w = wf2[kk * 8 + v];
            f2[4 * v + 0] += d * w.x;
            f2[4 * v + 1] += d * w.y;
            f2[4 * v + 2] += d * w.z;
            f2[4 * v + 3] += d * w.w;
        }
    }
    #pragma unroll
    for (int o = 0; o < 32; ++o) f2[o] = f2[o] > 0.f ? f2[o] : 0.f;

    float q = wlds[L_BF3];
    #pragma unroll
    for (int v = 0; v < 8; ++v) {
        float4 w = wf3[v];
        q += f2[4 * v + 0] * w.x + f2[4 * v + 1] * w.y
           + f2[4 * v + 2] * w.z + f2[4 * v + 3] * w.w;
    }

    if (half == 0) out[pair] = q;
}

extern "C" void kernel_launch(void* const* d_in, const int* in_sizes, int n_in,
                              void* d_out, int out_size, void* d_ws, size_t ws_size,
                              hipStream_t stream) {
    const float* Sg  = (const float*)d_in[0];
    const float* R   = (const float*)d_in[1];
    const float* W1  = (const float*)d_in[2];
    const float* b1  = (const float*)d_in[3];
    const float* W2  = (const float*)d_in[4];
    const float* b2  = (const float*)d_in[5];
    const float* Wf1 = (const float*)d_in[6];
    const float* bf1 = (const float*)d_in[7];
    const float* Wf2 = (const float*)d_in[8];
    const float* bf2 = (const float*)d_in[9];
    const float* Wf3 = (const float*)d_in[10];
    const float* bf3 = (const float*)d_in[11];
    float* out = (float*)d_out;

    dim3 grid((UI * 2) / 256), block(256);   // 2 lanes per pair
    dqn_v3<<<grid, block, 0, stream>>>(Sg, R, W1, b1, W2, b2,
                                       Wf1, bf1, Wf2, bf2, Wf3, bf3, out);
}

// Round 4
// 93.968 us; speedup vs baseline: 11.3338x; 11.3338x over previous
//
#include <hip/hip_runtime.h>

constexpr int U_ = 256;
constexpr int I_ = 512;
constexpr int J_ = 31;
constexpr int UI = U_ * I_;               // 131072 pairs
constexpr size_t D_BYTES = (size_t)UI * 20 * 4;   // 10.5 MB workspace for D

// ---------------- Phase 1: descriptor D[20] per pair (4 lanes/pair) ----------
// Lane g in [0,4) owns R-component l=g. Zero LDS; all weights are wave-uniform
// global reads (compiler scalarizes to s_load / SGPRs).
__global__ __launch_bounds__(256) void dqn_phase1(
    const float* __restrict__ Sg, const float* __restrict__ R,
    const float* __restrict__ W1, const float* __restrict__ b1,
    const float* __restrict__ W2, const float* __restrict__ b2,
    float* __restrict__ Dws)
{
    const int gt   = blockIdx.x * 256 + threadIdx.x;
    const int pair = gt >> 2;
    const int g    = gt & 3;

    const float* sg = Sg + (size_t)pair * (J_ * 3);
    const float* rr = R  + (size_t)pair * (J_ * 4);

    // Uniform weights -> SGPRs
    float w10[10], w11[10], w12[10], c1[10];
    #pragma unroll
    for (int p = 0; p < 10; ++p) {
        w10[p] = W1[p]; w11[p] = W1[10 + p]; w12[p] = W1[20 + p]; c1[p] = b1[p];
    }

    float M[10];
    float Rsg = 0.f;
    #pragma unroll
    for (int p = 0; p < 10; ++p) M[p] = 0.f;

    // j-loop with depth-1 prefetch
    float s0 = sg[0], s1 = sg[1], s2 = sg[2], r0 = rr[g];
    #pragma unroll 1
    for (int j = 0; j < J_; ++j) {
        float ns0 = 0.f, ns1 = 0.f, ns2 = 0.f, nr = 0.f;
        if (j + 1 < J_) {
            ns0 = sg[(j + 1) * 3 + 0];
            ns1 = sg[(j + 1) * 3 + 1];
            ns2 = sg[(j + 1) * 3 + 2];
            nr  = rr[(j + 1) * 4 + g];
        }
        #pragma unroll
        for (int p = 0; p < 10; ++p) {
            float t = c1[p] + s0 * w10[p] + s1 * w11[p] + s2 * w12[p];
            t = t > 0.f ? t : 0.f;       // ReLU
            M[p] += r0 * t;
        }
        Rsg += r0;
        s0 = ns0; s1 = ns1; s2 = ns2; r0 = nr;
    }

    // T2 row g: T2g[n] = sum_p M[p]*W2[p][n] + Rsg*b2[n]
    float T2g[10];
    #pragma unroll
    for (int n = 0; n < 10; ++n) T2g[n] = Rsg * b2[n];
    #pragma unroll
    for (int p = 0; p < 10; ++p) {
        float m = M[p];
        #pragma unroll
        for (int n = 0; n < 10; ++n) T2g[n] += m * W2[p * 10 + n];
    }

    // D[k*10+n] = sum over 4 lanes of T2g[k]*T2g[n]  (T1 == T2^T)
    float D[20];
    #pragma unroll
    for (int k = 0; k < 2; ++k)
        #pragma unroll
        for (int n = 0; n < 10; ++n) D[k * 10 + n] = T2g[k] * T2g[n];
    #pragma unroll
    for (int t = 0; t < 20; ++t) {
        D[t] += __shfl_xor(D[t], 1);
        D[t] += __shfl_xor(D[t], 2);
    }

    // Transposed store, static register indices per g-branch (no scratch).
    float* dw = Dws + pair;
    if (g == 0) {
        dw[0 * UI] = D[0];  dw[1 * UI] = D[1];  dw[2 * UI] = D[2];
        dw[3 * UI] = D[3];  dw[4 * UI] = D[4];
    } else if (g == 1) {
        dw[5 * UI] = D[5];  dw[6 * UI] = D[6];  dw[7 * UI] = D[7];
        dw[8 * UI] = D[8];  dw[9 * UI] = D[9];
    } else if (g == 2) {
        dw[10 * UI] = D[10]; dw[11 * UI] = D[11]; dw[12 * UI] = D[12];
        dw[13 * UI] = D[13]; dw[14 * UI] = D[14];
    } else {
        dw[15 * UI] = D[15]; dw[16 * UI] = D[16]; dw[17 * UI] = D[17];
        dw[18 * UI] = D[18]; dw[19 * UI] = D[19];
    }
}

// ---------------- Phase 2: fit MLP 20->32->32->1 (1 thread/pair) -------------
__global__ __launch_bounds__(256) void dqn_phase2(
    const float* __restrict__ Dws,
    const float* __restrict__ Wf1, const float* __restrict__ bf1,
    const float* __restrict__ Wf2, const float* __restrict__ bf2,
    const float* __restrict__ Wf3, const float* __restrict__ bf3,
    float* __restrict__ out)
{
    const int pair = blockIdx.x * 256 + threadIdx.x;

    float D[20];
    #pragma unroll
    for (int t = 0; t < 20; ++t) D[t] = Dws[(size_t)t * UI + pair];   // coalesced

    float f1[32];
    #pragma unroll
    for (int o = 0; o < 32; ++o) f1[o] = bf1[o];
    #pragma unroll
    for (int kk = 0; kk < 20; ++kk) {
        const float4* wrow = reinterpret_cast<const float4*>(Wf1 + kk * 32);
        float d = D[kk];
        #pragma unroll
        for (int v = 0; v < 8; ++v) {
            float4 w = wrow[v];
            f1[4 * v + 0] += d * w.x;
            f1[4 * v + 1] += d * w.y;
            f1[4 * v + 2] += d * w.z;
            f1[4 * v + 3] += d * w.w;
        }
    }
    #pragma unroll
    for (int o = 0; o < 32; ++o) f1[o] = f1[o] > 0.f ? f1[o] : 0.f;

    float f2[32];
    #pragma unroll
    for (int o = 0; o < 32; ++o) f2[o] = bf2[o];
    #pragma unroll
    for (int kk = 0; kk < 32; ++kk) {
        const float4* wrow = reinterpret_cast<const float4*>(Wf2 + kk * 32);
        float d = f1[kk];
        #pragma unroll
        for (int v = 0; v < 8; ++v) {
            float4 w = wrow[v];
            f2[4 * v + 0] += d * w.x;
            f2[4 * v + 1] += d * w.y;
            f2[4 * v + 2] += d * w.z;
            f2[4 * v + 3] += d * w.w;
        }
    }
    #pragma unroll
    for (int o = 0; o < 32; ++o) f2[o] = f2[o] > 0.f ? f2[o] : 0.f;

    float q = bf3[0];
    #pragma unroll
    for (int o = 0; o < 32; o += 4) {
        float4 w = *reinterpret_cast<const float4*>(Wf3 + o);
        q += f2[o + 0] * w.x + f2[o + 1] * w.y + f2[o + 2] * w.z + f2[o + 3] * w.w;
    }

    out[pair] = q;
}

// ---------------- Fallback: known-good fused v1 (if ws too small) ------------
struct Nb1 { float s0, s1, s2; float4 r; };
__device__ __forceinline__ Nb1 load_nb1(const float* __restrict__ sg,
                                        const float* __restrict__ rr, int j) {
    Nb1 d;
    d.s0 = sg[j * 3 + 0]; d.s1 = sg[j * 3 + 1]; d.s2 = sg[j * 3 + 2];
    d.r = *reinterpret_cast<const float4*>(rr + j * 4);
    return d;
}
__global__ __launch_bounds__(256, 2) void dqn_fused_fb(
    const float* __restrict__ Sg,  const float* __restrict__ R,
    const float* __restrict__ W1,  const float* __restrict__ b1,
    const float* __restrict__ W2,  const float* __restrict__ b2,
    const float* __restrict__ Wf1, const float* __restrict__ bf1,
    const float* __restrict__ Wf2, const float* __restrict__ bf2,
    const float* __restrict__ Wf3, const float* __restrict__ bf3,
    float* __restrict__ out)
{
    const int pair = blockIdx.x * 256 + threadIdx.x;
    const float* sg = Sg + (size_t)pair * (J_ * 3);
    const float* rr = R  + (size_t)pair * (J_ * 4);
    float w1[3][10], c1[10];
    #pragma unroll
    for (int k = 0; k < 3; ++k)
        #pragma unroll
        for (int p = 0; p < 10; ++p) w1[k][p] = W1[k * 10 + p];
    #pragma unroll
    for (int p = 0; p < 10; ++p) c1[p] = b1[p];
    float M[4][10]; float Rs[4] = {0.f,0.f,0.f,0.f};
    #pragma unroll
    for (int l = 0; l < 4; ++l)
        #pragma unroll
        for (int p = 0; p < 10; ++p) M[l][p] = 0.f;
    #pragma unroll 1
    for (int j = 0; j < J_; ++j) {
        Nb1 nb = load_nb1(sg, rr, j);
        float h[10];
        #pragma unroll
        for (int p = 0; p < 10; ++p) {
            float t = c1[p] + nb.s0*w1[0][p] + nb.s1*w1[1][p] + nb.s2*w1[2][p];
            h[p] = t > 0.f ? t : 0.f;
        }
        Rs[0]+=nb.r.x; Rs[1]+=nb.r.y; Rs[2]+=nb.r.z; Rs[3]+=nb.r.w;
        #pragma unroll
        for (int p = 0; p < 10; ++p) {
            M[0][p]+=nb.r.x*h[p]; M[1][p]+=nb.r.y*h[p];
            M[2][p]+=nb.r.z*h[p]; M[3][p]+=nb.r.w*h[p];
        }
    }
    float T2[4][10];
    #pragma unroll
    for (int l = 0; l < 4; ++l)
        #pragma unroll
        for (int n = 0; n < 10; ++n) T2[l][n] = Rs[l] * b2[n];
    #pragma unroll
    for (int p = 0; p < 10; ++p) {
        #pragma unroll
        for (int l = 0; l < 4; ++l) {
            float m = M[l][p];
            #pragma unroll
            for (int n = 0; n < 10; ++n) T2[l][n] += m * W2[p * 10 + n];
        }
    }
    float D[20];
    #pragma unroll
    for (int k = 0; k < 2; ++k)
        #pragma unroll
        for (int n = 0; n < 10; ++n)
            D[k*10+n] = T2[0][k]*T2[0][n] + T2[1][k]*T2[1][n]
                      + T2[2][k]*T2[2][n] + T2[3][k]*T2[3][n];
    float f1[32];
    #pragma unroll
    for (int o = 0; o < 32; ++o) f1[o] = bf1[o];
    #pragma unroll
    for (int kk = 0; kk < 20; ++kk) {
        const float4* wrow = reinterpret_cast<const float4*>(Wf1 + kk * 32);
        float d = D[kk];
        #pragma unroll
        for (int v = 0; v < 8; ++v) {
            float4 w = wrow[v];
            f1[4*v+0]+=d*w.x; f1[4*v+1]+=d*w.y; f1[4*v+2]+=d*w.z; f1[4*v+3]+=d*w.w;
        }
    }
    #pragma unroll
    for (int o = 0; o < 32; ++o) f1[o] = f1[o] > 0.f ? f1[o] : 0.f;
    float f2[32];
    #pragma unroll
    for (int o = 0; o < 32; ++o) f2[o] = bf2[o];
    #pragma unroll
    for (int kk = 0; kk < 32; ++kk) {
        const float4* wrow = reinterpret_cast<const float4*>(Wf2 + kk * 32);
        float d = f1[kk];
        #pragma unroll
        for (int v = 0; v < 8; ++v) {
            float4 w = wrow[v];
            f2[4*v+0]+=d*w.x; f2[4*v+1]+=d*w.y; f2[4*v+2]+=d*w.z; f2[4*v+3]+=d*w.w;
        }
    }
    #pragma unroll
    for (int o = 0; o < 32; ++o) f2[o] = f2[o] > 0.f ? f2[o] : 0.f;
    float q = bf3[0];
    #pragma unroll
    for (int o = 0; o < 32; o += 4) {
        float4 w = *reinterpret_cast<const float4*>(Wf3 + o);
        q += f2[o+0]*w.x + f2[o+1]*w.y + f2[o+2]*w.z + f2[o+3]*w.w;
    }
    out[pair] = q;
}

extern "C" void kernel_launch(void* const* d_in, const int* in_sizes, int n_in,
                              void* d_out, int out_size, void* d_ws, size_t ws_size,
                              hipStream_t stream) {
    const float* Sg  = (const float*)d_in[0];
    const float* R   = (const float*)d_in[1];
    const float* W1  = (const float*)d_in[2];
    const float* b1  = (const float*)d_in[3];
    const float* W2  = (const float*)d_in[4];
    const float* b2  = (const float*)d_in[5];
    const float* Wf1 = (const float*)d_in[6];
    const float* bf1 = (const float*)d_in[7];
    const float* Wf2 = (const float*)d_in[8];
    const float* bf2 = (const float*)d_in[9];
    const float* Wf3 = (const float*)d_in[10];
    const float* bf3 = (const float*)d_in[11];
    float* out = (float*)d_out;

    if (ws_size >= D_BYTES) {
        float* Dws = (float*)d_ws;
        dqn_phase1<<<dim3((UI * 4) / 256), dim3(256), 0, stream>>>(
            Sg, R, W1, b1, W2, b2, Dws);
        dqn_phase2<<<dim3(UI / 256), dim3(256), 0, stream>>>(
            Dws, Wf1, bf1, Wf2, bf2, Wf3, bf3, out);
    } else {
        dqn_fused_fb<<<dim3(UI / 256), dim3(256), 0, stream>>>(
            Sg, R, W1, b1, W2, b2, Wf1, bf1, Wf2, bf2, Wf3, bf3, out);
    }
}

// Round 5
// 74.013 us; speedup vs baseline: 14.3896x; 1.2696x over previous
//
#include <hip/hip_runtime.h>

constexpr int U_ = 256;
constexpr int I_ = 512;
constexpr int J_ = 31;
constexpr int UI = U_ * I_;               // 131072 pairs
constexpr size_t D_BYTES = (size_t)UI * 20 * 4;   // 10.5 MB workspace for D

// ---------------- Phase 1: descriptor D[20] per pair (4 lanes/pair) ----------
// Lane g in [0,4) owns R-component l=g; depth-4 software pipeline over j keeps
// ~16 loads (112 B) in flight per thread to cover L2/HBM latency.
struct Nb { float s0, s1, s2, r; };

__global__ __launch_bounds__(256) void dqn_phase1(
    const float* __restrict__ Sg, const float* __restrict__ R,
    const float* __restrict__ W1, const float* __restrict__ b1,
    const float* __restrict__ W2, const float* __restrict__ b2,
    float* __restrict__ Dws)
{
    const int gt   = blockIdx.x * 256 + threadIdx.x;
    const int pair = gt >> 2;
    const int g    = gt & 3;

    const float* sg = Sg + (size_t)pair * (J_ * 3);
    const float* rr = R  + (size_t)pair * (J_ * 4) + g;

    // Uniform weights -> SGPRs (compiler scalarizes)
    float w10[10], w11[10], w12[10], c1w[10];
    #pragma unroll
    for (int p = 0; p < 10; ++p) {
        w10[p] = W1[p]; w11[p] = W1[10 + p]; w12[p] = W1[20 + p]; c1w[p] = b1[p];
    }

    float M[10];
    float Rsg = 0.f;
    #pragma unroll
    for (int p = 0; p < 10; ++p) M[p] = 0.f;

    auto ld = [&](int j) {
        Nb d;
        d.s0 = sg[j * 3 + 0];
        d.s1 = sg[j * 3 + 1];
        d.s2 = sg[j * 3 + 2];
        d.r  = rr[j * 4];          // 4 lanes -> 16B contiguous per pair
        return d;
    };
    auto proc = [&](const Nb& nb) {
        #pragma unroll
        for (int p = 0; p < 10; ++p) {
            float t = c1w[p] + nb.s0 * w10[p] + nb.s1 * w11[p] + nb.s2 * w12[p];
            t = t > 0.f ? t : 0.f;     // ReLU
            M[p] += nb.r * t;
        }
        Rsg += nb.r;
    };

    // Depth-4 pipeline: stage j..j+3, load j+4..j+7 while processing.
    Nb c0 = ld(0), c1 = ld(1), c2 = ld(2), c3 = ld(3);
    #pragma unroll 1
    for (int jb = 0; jb < 24; jb += 4) {
        Nb n0 = ld(jb + 4), n1 = ld(jb + 5), n2 = ld(jb + 6), n3 = ld(jb + 7);
        proc(c0); proc(c1); proc(c2); proc(c3);
        c0 = n0; c1 = n1; c2 = n2; c3 = n3;
    }
    // c0..c3 hold j=24..27; issue tail loads (28..30) before processing them.
    Nb t0 = ld(28), t1 = ld(29), t2 = ld(30);
    proc(c0); proc(c1); proc(c2); proc(c3);
    proc(t0); proc(t1); proc(t2);

    // T2 row g: T2g[n] = sum_p M[p]*W2[p][n] + Rsg*b2[n]
    float T2g[10];
    #pragma unroll
    for (int n = 0; n < 10; ++n) T2g[n] = Rsg * b2[n];
    #pragma unroll
    for (int p = 0; p < 10; ++p) {
        float m = M[p];
        #pragma unroll
        for (int n = 0; n < 10; ++n) T2g[n] += m * W2[p * 10 + n];
    }

    // D[k*10+n] = sum over 4 lanes of T2g[k]*T2g[n]  (T1 == T2^T)
    float D[20];
    #pragma unroll
    for (int k = 0; k < 2; ++k)
        #pragma unroll
        for (int n = 0; n < 10; ++n) D[k * 10 + n] = T2g[k] * T2g[n];
    #pragma unroll
    for (int t = 0; t < 20; ++t) {
        D[t] += __shfl_xor(D[t], 1);
        D[t] += __shfl_xor(D[t], 2);
    }

    // Transposed store, static register indices per g-branch (no scratch).
    float* dw = Dws + pair;
    if (g == 0) {
        dw[0 * UI] = D[0];  dw[1 * UI] = D[1];  dw[2 * UI] = D[2];
        dw[3 * UI] = D[3];  dw[4 * UI] = D[4];
    } else if (g == 1) {
        dw[5 * UI] = D[5];  dw[6 * UI] = D[6];  dw[7 * UI] = D[7];
        dw[8 * UI] = D[8];  dw[9 * UI] = D[9];
    } else if (g == 2) {
        dw[10 * UI] = D[10]; dw[11 * UI] = D[11]; dw[12 * UI] = D[12];
        dw[13 * UI] = D[13]; dw[14 * UI] = D[14];
    } else {
        dw[15 * UI] = D[15]; dw[16 * UI] = D[16]; dw[17 * UI] = D[17];
        dw[18 * UI] = D[18]; dw[19 * UI] = D[19];
    }
}

// ---------------- Phase 2: fit MLP 20->32->32->1 (1 thread/pair) -------------
__global__ __launch_bounds__(256) void dqn_phase2(
    const float* __restrict__ Dws,
    const float* __restrict__ Wf1, const float* __restrict__ bf1,
    const float* __restrict__ Wf2, const float* __restrict__ bf2,
    const float* __restrict__ Wf3, const float* __restrict__ bf3,
    float* __restrict__ out)
{
    const int pair = blockIdx.x * 256 + threadIdx.x;

    float D[20];
    #pragma unroll
    for (int t = 0; t < 20; ++t) D[t] = Dws[(size_t)t * UI + pair];   // coalesced

    float f1[32];
    #pragma unroll
    for (int o = 0; o < 32; ++o) f1[o] = bf1[o];
    #pragma unroll
    for (int kk = 0; kk < 20; ++kk) {
        const float4* wrow = reinterpret_cast<const float4*>(Wf1 + kk * 32);
        float d = D[kk];
        #pragma unroll
        for (int v = 0; v < 8; ++v) {
            float4 w = wrow[v];
            f1[4 * v + 0] += d * w.x;
            f1[4 * v + 1] += d * w.y;
            f1[4 * v + 2] += d * w.z;
            f1[4 * v + 3] += d * w.w;
        }
    }
    #pragma unroll
    for (int o = 0; o < 32; ++o) f1[o] = f1[o] > 0.f ? f1[o] : 0.f;

    float f2[32];
    #pragma unroll
    for (int o = 0; o < 32; ++o) f2[o] = bf2[o];
    #pragma unroll
    for (int kk = 0; kk < 32; ++kk) {
        const float4* wrow = reinterpret_cast<const float4*>(Wf2 + kk * 32);
        float d = f1[kk];
        #pragma unroll
        for (int v = 0; v < 8; ++v) {
            float4 w = wrow[v];
            f2[4 * v + 0] += d * w.x;
            f2[4 * v + 1] += d * w.y;
            f2[4 * v + 2] += d * w.z;
            f2[4 * v + 3] += d * w.w;
        }
    }
    #pragma unroll
    for (int o = 0; o < 32; ++o) f2[o] = f2[o] > 0.f ? f2[o] : 0.f;

    float q = bf3[0];
    #pragma unroll
    for (int o = 0; o < 32; o += 4) {
        float4 w = *reinterpret_cast<const float4*>(Wf3 + o);
        q += f2[o + 0] * w.x + f2[o + 1] * w.y + f2[o + 2] * w.z + f2[o + 3] * w.w;
    }

    out[pair] = q;
}

// ---------------- Fallback: known-good fused v1 (if ws too small) ------------
struct Nb1 { float s0, s1, s2; float4 r; };
__device__ __forceinline__ Nb1 load_nb1(const float* __restrict__ sg,
                                        const float* __restrict__ rr, int j) {
    Nb1 d;
    d.s0 = sg[j * 3 + 0]; d.s1 = sg[j * 3 + 1]; d.s2 = sg[j * 3 + 2];
    d.r = *reinterpret_cast<const float4*>(rr + j * 4);
    return d;
}
__global__ __launch_bounds__(256, 2) void dqn_fused_fb(
    const float* __restrict__ Sg,  const float* __restrict__ R,
    const float* __restrict__ W1,  const float* __restrict__ b1,
    const float* __restrict__ W2,  const float* __restrict__ b2,
    const float* __restrict__ Wf1, const float* __restrict__ bf1,
    const float* __restrict__ Wf2, const float* __restrict__ bf2,
    const float* __restrict__ Wf3, const float* __restrict__ bf3,
    float* __restrict__ out)
{
    const int pair = blockIdx.x * 256 + threadIdx.x;
    const float* sg = Sg + (size_t)pair * (J_ * 3);
    const float* rr = R  + (size_t)pair * (J_ * 4);
    float w1[3][10], c1[10];
    #pragma unroll
    for (int k = 0; k < 3; ++k)
        #pragma unroll
        for (int p = 0; p < 10; ++p) w1[k][p] = W1[k * 10 + p];
    #pragma unroll
    for (int p = 0; p < 10; ++p) c1[p] = b1[p];
    float M[4][10]; float Rs[4] = {0.f,0.f,0.f,0.f};
    #pragma unroll
    for (int l = 0; l < 4; ++l)
        #pragma unroll
        for (int p = 0; p < 10; ++p) M[l][p] = 0.f;
    #pragma unroll 1
    for (int j = 0; j < J_; ++j) {
        Nb1 nb = load_nb1(sg, rr, j);
        float h[10];
        #pragma unroll
        for (int p = 0; p < 10; ++p) {
            float t = c1[p] + nb.s0*w1[0][p] + nb.s1*w1[1][p] + nb.s2*w1[2][p];
            h[p] = t > 0.f ? t : 0.f;
        }
        Rs[0]+=nb.r.x; Rs[1]+=nb.r.y; Rs[2]+=nb.r.z; Rs[3]+=nb.r.w;
        #pragma unroll
        for (int p = 0; p < 10; ++p) {
            M[0][p]+=nb.r.x*h[p]; M[1][p]+=nb.r.y*h[p];
            M[2][p]+=nb.r.z*h[p]; M[3][p]+=nb.r.w*h[p];
        }
    }
    float T2[4][10];
    #pragma unroll
    for (int l = 0; l < 4; ++l)
        #pragma unroll
        for (int n = 0; n < 10; ++n) T2[l][n] = Rs[l] * b2[n];
    #pragma unroll
    for (int p = 0; p < 10; ++p) {
        #pragma unroll
        for (int l = 0; l < 4; ++l) {
            float m = M[l][p];
            #pragma unroll
            for (int n = 0; n < 10; ++n) T2[l][n] += m * W2[p * 10 + n];
        }
    }
    float D[20];
    #pragma unroll
    for (int k = 0; k < 2; ++k)
        #pragma unroll
        for (int n = 0; n < 10; ++n)
            D[k*10+n] = T2[0][k]*T2[0][n] + T2[1][k]*T2[1][n]
                      + T2[2][k]*T2[2][n] + T2[3][k]*T2[3][n];
    float f1[32];
    #pragma unroll
    for (int o = 0; o < 32; ++o) f1[o] = bf1[o];
    #pragma unroll
    for (int kk = 0; kk < 20; ++kk) {
        const float4* wrow = reinterpret_cast<const float4*>(Wf1 + kk * 32);
        float d = D[kk];
        #pragma unroll
        for (int v = 0; v < 8; ++v) {
            float4 w = wrow[v];
            f1[4*v+0]+=d*w.x; f1[4*v+1]+=d*w.y; f1[4*v+2]+=d*w.z; f1[4*v+3]+=d*w.w;
        }
    }
    #pragma unroll
    for (int o = 0; o < 32; ++o) f1[o] = f1[o] > 0.f ? f1[o] : 0.f;
    float f2[32];
    #pragma unroll
    for (int o = 0; o < 32; ++o) f2[o] = bf2[o];
    #pragma unroll
    for (int kk = 0; kk < 32; ++kk) {
        const float4* wrow = reinterpret_cast<const float4*>(Wf2 + kk * 32);
        float d = f1[kk];
        #pragma unroll
        for (int v = 0; v < 8; ++v) {
            float4 w = wrow[v];
            f2[4*v+0]+=d*w.x; f2[4*v+1]+=d*w.y; f2[4*v+2]+=d*w.z; f2[4*v+3]+=d*w.w;
        }
    }
    #pragma unroll
    for (int o = 0; o < 32; ++o) f2[o] = f2[o] > 0.f ? f2[o] : 0.f;
    float q = bf3[0];
    #pragma unroll
    for (int o = 0; o < 32; o += 4) {
        float4 w = *reinterpret_cast<const float4*>(Wf3 + o);
        q += f2[o+0]*w.x + f2[o+1]*w.y + f2[o+2]*w.z + f2[o+3]*w.w;
    }
    out[pair] = q;
}

extern "C" void kernel_launch(void* const* d_in, const int* in_sizes, int n_in,
                              void* d_out, int out_size, void* d_ws, size_t ws_size,
                              hipStream_t stream) {
    const float* Sg  = (const float*)d_in[0];
    const float* R   = (const float*)d_in[1];
    const float* W1  = (const float*)d_in[2];
    const float* b1  = (const float*)d_in[3];
    const float* W2  = (const float*)d_in[4];
    const float* b2  = (const float*)d_in[5];
    const float* Wf1 = (const float*)d_in[6];
    const float* bf1 = (const float*)d_in[7];
    const float* Wf2 = (const float*)d_in[8];
    const float* bf2 = (const float*)d_in[9];
    const float* Wf3 = (const float*)d_in[10];
    const float* bf3 = (const float*)d_in[11];
    float* out = (float*)d_out;

    if (ws_size >= D_BYTES) {
        float* Dws = (float*)d_ws;
        dqn_phase1<<<dim3((UI * 4) / 256), dim3(256), 0, stream>>>(
            Sg, R, W1, b1, W2, b2, Dws);
        dqn_phase2<<<dim3(UI / 256), dim3(256), 0, stream>>>(
            Dws, Wf1, bf1, Wf2, bf2, Wf3, bf3, out);
    } else {
        dqn_fused_fb<<<dim3(UI / 256), dim3(256), 0, stream>>>(
            Sg, R, W1, b1, W2, b2, Wf1, bf1, Wf2, bf2, Wf3, bf3, out);
    }
}

// Round 6
// 71.687 us; speedup vs baseline: 14.8565x; 1.0324x over previous
//
#include <hip/hip_runtime.h>

constexpr int U_ = 256;
constexpr int I_ = 512;
constexpr int J_ = 31;
constexpr int UI = U_ * I_;     // 131072 pairs

// Single fused kernel. 4 lanes per pair.
//  - j-loop: lane g handles neighbors jb+g (j-split): coalesced float4 R +
//    3-dword Sg per lane, h computed once per neighbor (no 4x redundancy).
//  - M[4][10]+Rs[4] butterfly all-reduce across the 4-lane group.
//  - T2[4][10], D[20] redundant on all 4 lanes (static indices only).
//  - fit MLP split 2-way by lane parity (16 of 32 outputs each), one
//    shfl_xor exchange of f1, partner rows via runtime ADDRESS arithmetic.
__global__ __launch_bounds__(256) void dqn_v6(
    const float* __restrict__ Sg,  const float* __restrict__ R,
    const float* __restrict__ W1,  const float* __restrict__ b1,
    const float* __restrict__ W2,  const float* __restrict__ b2,
    const float* __restrict__ Wf1, const float* __restrict__ bf1,
    const float* __restrict__ Wf2, const float* __restrict__ bf2,
    const float* __restrict__ Wf3, const float* __restrict__ bf3,
    float* __restrict__ out)
{
    const int gt   = blockIdx.x * 256 + threadIdx.x;
    const int pair = gt >> 2;
    const int g    = gt & 3;

    const float* sg = Sg + (size_t)pair * (3 * J_);
    const float* rr = R  + (size_t)pair * (4 * J_);

    // Embedding weights: uniform addresses -> scalarized to SGPRs.
    float w10[10], w11[10], w12[10], c1[10];
    #pragma unroll
    for (int p = 0; p < 10; ++p) {
        w10[p] = W1[p]; w11[p] = W1[10 + p]; w12[p] = W1[20 + p]; c1[p] = b1[p];
    }

    float M[4][10];
    float Rs[4] = {0.f, 0.f, 0.f, 0.f};
    #pragma unroll
    for (int l = 0; l < 4; ++l)
        #pragma unroll
        for (int p = 0; p < 10; ++p) M[l][p] = 0.f;

    // ---- j-loop: lane g processes neighbor jb+g ----
    auto LD = [&](int jb, float4& r4, float& s0, float& s1, float& s2) {
        int j  = jb + g;
        int jc = j < J_ ? j : (J_ - 1);          // clamp (lane 3 of last block)
        r4 = *reinterpret_cast<const float4*>(rr + jc * 4);   // 64B/group
        const float* sp = sg + jc * 3;                         // 48B/group
        s0 = sp[0]; s1 = sp[1]; s2 = sp[2];
    };
    auto PROC = [&](int jb, const float4& r4, float s0, float s1, float s2) {
        float m  = (jb + g) < J_ ? 1.f : 0.f;
        float rx = r4.x * m, ry = r4.y * m, rz = r4.z * m, rw = r4.w * m;
        float h[10];
        #pragma unroll
        for (int p = 0; p < 10; ++p) {
            float t = c1[p] + s0 * w10[p] + s1 * w11[p] + s2 * w12[p];
            h[p] = t > 0.f ? t : 0.f;            // ReLU
        }
        #pragma unroll
        for (int p = 0; p < 10; ++p) {
            M[0][p] += rx * h[p];
            M[1][p] += ry * h[p];
            M[2][p] += rz * h[p];
            M[3][p] += rw * h[p];
        }
        Rs[0] += rx; Rs[1] += ry; Rs[2] += rz; Rs[3] += rw;
    };

    // Depth-2 block pipeline over 8 blocks of 4 neighbors (jb = 0..28).
    float4 rA, rB; float a0, a1, a2, e0, e1, e2;
    LD(0, rA, a0, a1, a2);
    #pragma unroll 1
    for (int jb = 0; jb < 24; jb += 4) {
        LD(jb + 4, rB, e0, e1, e2);
        PROC(jb, rA, a0, a1, a2);
        rA = rB; a0 = e0; a1 = e1; a2 = e2;
    }
    LD(28, rB, e0, e1, e2);
    PROC(24, rA, a0, a1, a2);
    PROC(28, rB, e0, e1, e2);

    // ---- all-reduce M, Rs across the 4-lane group (static indices) ----
    #pragma unroll
    for (int l = 0; l < 4; ++l) {
        #pragma unroll
        for (int p = 0; p < 10; ++p) {
            M[l][p] += __shfl_xor(M[l][p], 1);
            M[l][p] += __shfl_xor(M[l][p], 2);
        }
        Rs[l] += __shfl_xor(Rs[l], 1);
        Rs[l] += __shfl_xor(Rs[l], 2);
    }

    // ---- T2 = M @ W2 + Rs x b2  (redundant on all 4 lanes; W2 uniform) ----
    float T2[4][10];
    #pragma unroll
    for (int l = 0; l < 4; ++l)
        #pragma unroll
        for (int n = 0; n < 10; ++n) T2[l][n] = Rs[l] * b2[n];
    #pragma unroll
    for (int p = 0; p < 10; ++p) {
        float w2row[10];
        #pragma unroll
        for (int n = 0; n < 10; ++n) w2row[n] = W2[p * 10 + n];
        #pragma unroll
        for (int l = 0; l < 4; ++l) {
            float m = M[l][p];
            #pragma unroll
            for (int n = 0; n < 10; ++n) T2[l][n] += m * w2row[n];
        }
    }

    // ---- D[k*10+n] = sum_l T2[l][k]*T2[l][n], k<2 (T1 == T2^T) ----
    float D[20];
    #pragma unroll
    for (int k = 0; k < 2; ++k)
        #pragma unroll
        for (int n = 0; n < 10; ++n)
            D[k * 10 + n] = T2[0][k] * T2[0][n] + T2[1][k] * T2[1][n]
                          + T2[2][k] * T2[2][n] + T2[3][k] * T2[3][n];

    // ---- fit MLP, 2-way output split by parity (h16 = 0 or 16) ----
    const int h16 = (g & 1) * 16;

    // layer 1: outs [h16, h16+16)
    float F[16];
    {
        const float4* bv = reinterpret_cast<const float4*>(bf1 + h16);
        #pragma unroll
        for (int v = 0; v < 4; ++v) {
            float4 b4 = bv[v];
            F[4*v+0] = b4.x; F[4*v+1] = b4.y; F[4*v+2] = b4.z; F[4*v+3] = b4.w;
        }
    }
    #pragma unroll
    for (int kk = 0; kk < 20; ++kk) {
        float d = D[kk];
        const float4* wr = reinterpret_cast<const float4*>(Wf1 + kk * 32 + h16);
        #pragma unroll
        for (int v = 0; v < 4; ++v) {
            float4 w = wr[v];
            F[4*v+0] += d * w.x; F[4*v+1] += d * w.y;
            F[4*v+2] += d * w.z; F[4*v+3] += d * w.w;
        }
    }
    #pragma unroll
    for (int i = 0; i < 16; ++i) F[i] = F[i] > 0.f ? F[i] : 0.f;

    // exchange: partner's 16 f1 values
    float Fo[16];
    #pragma unroll
    for (int i = 0; i < 16; ++i) Fo[i] = __shfl_xor(F[i], 1);

    // layer 2: outs [h16, h16+16); rows h16+i use F, rows (16-h16)+i use Fo
    float G[16];
    {
        const float4* bv = reinterpret_cast<const float4*>(bf2 + h16);
        #pragma unroll
        for (int v = 0; v < 4; ++v) {
            float4 b4 = bv[v];
            G[4*v+0] = b4.x; G[4*v+1] = b4.y; G[4*v+2] = b4.z; G[4*v+3] = b4.w;
        }
    }
    {
        const float* rowA = Wf2 + h16 * 32 + h16;          // my f1-slice rows
        const float* rowB = Wf2 + (16 - h16) * 32 + h16;   // partner's rows
        #pragma unroll
        for (int i = 0; i < 16; ++i) {
            float dA = F[i];
            const float4* wa = reinterpret_cast<const float4*>(rowA + i * 32);
            #pragma unroll
            for (int v = 0; v < 4; ++v) {
                float4 w = wa[v];
                G[4*v+0] += dA * w.x; G[4*v+1] += dA * w.y;
                G[4*v+2] += dA * w.z; G[4*v+3] += dA * w.w;
            }
            float dB = Fo[i];
            const float4* wb = reinterpret_cast<const float4*>(rowB + i * 32);
            #pragma unroll
            for (int v = 0; v < 4; ++v) {
                float4 w = wb[v];
                G[4*v+0] += dB * w.x; G[4*v+1] += dB * w.y;
                G[4*v+2] += dB * w.z; G[4*v+3] += dB * w.w;
            }
        }
    }
    #pragma unroll
    for (int i = 0; i < 16; ++i) G[i] = G[i] > 0.f ? G[i] : 0.f;

    // layer 3: partial dot over my 16 outs, then pairwise sum
    float qp = 0.f;
    {
        const float4* w3 = reinterpret_cast<const float4*>(Wf3 + h16);
        #pragma unroll
        for (int v = 0; v < 4; ++v) {
            float4 w = w3[v];
            qp += G[4*v+0] * w.x + G[4*v+1] * w.y
                + G[4*v+2] * w.z + G[4*v+3] * w.w;
        }
    }
    qp += __shfl_xor(qp, 1);
    float q = qp + bf3[0];

    if (g == 0) out[pair] = q;
}

extern "C" void kernel_launch(void* const* d_in, const int* in_sizes, int n_in,
                              void* d_out, int out_size, void* d_ws, size_t ws_size,
                              hipStream_t stream) {
    const float* Sg  = (const float*)d_in[0];
    const float* R   = (const float*)d_in[1];
    const float* W1  = (const float*)d_in[2];
    const float* b1  = (const float*)d_in[3];
    const float* W2  = (const float*)d_in[4];
    const float* b2  = (const float*)d_in[5];
    const float* Wf1 = (const float*)d_in[6];
    const float* bf1 = (const float*)d_in[7];
    const float* Wf2 = (const float*)d_in[8];
    const float* bf2 = (const float*)d_in[9];
    const float* Wf3 = (const float*)d_in[10];
    const float* bf3 = (const float*)d_in[11];
    float* out = (float*)d_out;

    dim3 grid((UI * 4) / 256), block(256);   // 4 lanes per pair
    dqn_v6<<<grid, block, 0, stream>>>(Sg, R, W1, b1, W2, b2,
                                       Wf1, bf1, Wf2, bf2, Wf3, bf3, out);
}